// Round 15
// baseline (64.666 us; speedup 1.0000x reference)
//
#include <hip/hip_runtime.h>
#include <hip/hip_cooperative_groups.h>
#include <cstddef>

// Problem constants (from reference)
constexpr int Bn = 64;     // batch
constexpr int In = 2048;   // input capsules
constexpr int Dk = 8;      // input dim
constexpr int Kc = 16;     // output capsules
constexpr int En = 16;     // output dim
constexpr float EPS = 1e-7f;

// Decomposition (R8/R12 measured optimum; R9/R11/R13 sweeps all worse):
// block = (p, g) tile of 8 i's x 16 batches, 4 waves; wave owns 4 batches x
// all 8 i's -> disjoint outputs, barrier-free iter. 1024 blocks co-resident.
constexpr int IB   = 8;            // i's per block
constexpr int P    = In / IB;      // 256 i-chunks
constexpr int BSET = 16;           // batches per block (4 per wave)
constexpr int NBG  = Bn / BSET;    // 4 batch groups
constexpr int BLOCKS = P * NBG;    // 1024
constexpr int THREADS = 256;       // 4 waves
constexpr int PPX  = P / 8;        // 32 p-chunks per XCD (2 MB of W < 4 MB L2)

// Packed fp32 pair -> v_pk_fma_f32. Statically indexed (rule-#20-safe).
typedef float v2f __attribute__((ext_vector_type(2)));
__device__ __forceinline__ v2f fma2(v2f a, v2f b, v2f c) {
    return __builtin_elementwise_fma(a, b, c);
}
__device__ __forceinline__ v2f splat2(float s) { return (v2f){s, s}; }

// DPP cross-lane add on the VALU pipe.
// ctrl: 0xB1 = quad_perm xor1, 0x4E = quad_perm xor2, 0x124/0x128 = row_ror 4/8
template<int CTRL>
__device__ __forceinline__ float dpp_add(float v) {
    int r = __builtin_amdgcn_update_dpp(0, __float_as_int(v), CTRL, 0xF, 0xF, true);
    return v + __int_as_float(r);
}

// ---------------- custom two-level grid barrier ----------------
// cg::grid.sync() at 1024 blocks = 1024 serialized same-line atomics + naive
// spin (~5-6 us each; 5 barriers ~ 25-30 us of R14's 64). Two-level version:
// 8 per-XCD arrival lines (parallel atomic streams, 128 adds each) -> master
// line (8 adds); lead thread spins with s_sleep; acquire/release via
// __hip_atomic (AGENT scope). Counters zeroed by hipMemsetAsync EVERY launch
// (replay-safe: harness does not re-poison ws between graph replays).
// Layout per phase: 256 ints; xcd counter at [phase*256 + xcd*16], master at
// [phase*256 + 240]. ARRIVE: whether this block arrives (others only wait).
__device__ __forceinline__ void grid_bar(int* __restrict__ bar, int phase,
                                         int bid, int t, bool arrive,
                                         int per_xcd_target)
{
    __syncthreads();                        // all block's stores issued
    if (t == 0) {
        int* slot = bar + phase * 256;
        if (arrive) {
            __threadfence();                // release: device-visible stores
            const int xcd = bid & 7;
            const int prev = __hip_atomic_fetch_add(slot + xcd * 16, 1,
                    __ATOMIC_ACQ_REL, __HIP_MEMORY_SCOPE_AGENT);
            if (prev == per_xcd_target - 1)
                __hip_atomic_fetch_add(slot + 240, 1,
                        __ATOMIC_ACQ_REL, __HIP_MEMORY_SCOPE_AGENT);
        }
        while (__hip_atomic_load(slot + 240, __ATOMIC_ACQUIRE,
                                 __HIP_MEMORY_SCOPE_AGENT) < 8)
            __builtin_amdgcn_s_sleep(2);
        __threadfence();                    // acquire: invalidate L1 for the CU
    }
    __syncthreads();                        // release the block
}

// One routing iteration for a (p, g) tile (R14's pk-math body, unchanged).
template<bool UNIFORM>
__device__ __forceinline__ void iter_body(const float* __restrict__ smemx,
        const float* __restrict__ W, const float* __restrict__ vsg,
        float* __restrict__ partial, int p, int b0, int i0, int t)
{
    const int lane = t & 63;
    const int wvi  = t >> 6;                // 0..3
    const int k    = lane >> 2;             // output capsule
    const int e4   = (lane & 3) << 2;       // first of 4 output dims
    const int bw   = b0 + (wvi << 2);       // this wave's first batch

    v2f vlo[4], vhi[4];
    if (!UNIFORM) {
        #pragma unroll
        for (int b4 = 0; b4 < 4; ++b4) {
            const float4 vv = *(const float4*)(vsg + ((bw + b4) << 8) + k * 16 + e4);
            vlo[b4] = (v2f){vv.x, vv.y};
            vhi[b4] = (v2f){vv.z, vv.w};
        }
    }

    v2f alo[4], ahi[4];
    #pragma unroll
    for (int b4 = 0; b4 < 4; ++b4) { alo[b4] = (v2f){0.f, 0.f}; ahi[b4] = (v2f){0.f, 0.f}; }

    #pragma unroll 2
    for (int ii = 0; ii < IB; ++ii) {
        const int i = i0 + ii;
        const float* wp = W + (size_t)i * (Kc * Dk * En) + k * (Dk * En) + e4;
        v2f wlo[8], whi[8];
        #pragma unroll
        for (int d = 0; d < 8; ++d) {
            const float4 wv = *(const float4*)(wp + d * En);
            wlo[d] = (v2f){wv.x, wv.y};
            whi[d] = (v2f){wv.z, wv.w};
        }

        #pragma unroll
        for (int b4 = 0; b4 < 4; ++b4) {
            const int bl = (wvi << 2) + b4;
            const float* xp = smemx + (((bl << 3) + ii) << 3);  // [bl][ii][*]
            const float4 x0 = *(const float4*)xp;
            const float4 x1 = *(const float4*)(xp + 4);
            const float xs8[8] = {x0.x, x0.y, x0.z, x0.w, x1.x, x1.y, x1.z, x1.w};

            v2f ulo = (v2f){0.f, 0.f}, uhi = (v2f){0.f, 0.f};
            #pragma unroll
            for (int d = 0; d < 8; ++d) {
                const v2f xd = splat2(xs8[d]);
                ulo = fma2(xd, wlo[d], ulo);    // v_pk_fma_f32
                uhi = fma2(xd, whi[d], uhi);
            }

            if (UNIFORM) {
                alo[b4] += ulo;
                ahi[b4] += uhi;
            } else {
                v2f t2 = ulo * vlo[b4];
                t2 = fma2(uhi, vhi[b4], t2);
                float tt = t2.x + t2.y;
                tt = dpp_add<0xB1>(tt);         // e-reduce: quad xor 1
                tt = dpp_add<0x4E>(tt);         // e-reduce: quad xor 2
                const float pe = __expf(tt);    // no max-sub: |tt| small
                float den = dpp_add<0x124>(pe); // k-sum in row: ror 4
                den = dpp_add<0x128>(den);      // k-sum in row: ror 8
                den += __shfl_xor(den, 16);     // cross-row
                den += __shfl_xor(den, 32);
                const float c = pe * __builtin_amdgcn_rcpf(den);
                const v2f cc = splat2(c);
                alo[b4] = fma2(cc, ulo, alo[b4]);
                ahi[b4] = fma2(cc, uhi, ahi[b4]);
            }
        }
    }

    #pragma unroll
    for (int b4 = 0; b4 < 4; ++b4) {
        *(float4*)(partial + ((size_t)(bw + b4) * P + p) * 256 + k * 16 + e4) =
            make_float4(alo[b4].x, alo[b4].y, ahi[b4].x, ahi[b4].y);
    }
}

// Sum the P=256 partials, squash, optional vprev add (unchanged from R14).
__device__ __forceinline__ void reduce_phase(float* red,
        const float* __restrict__ partial, float scale,
        const float* __restrict__ vprev, float* __restrict__ vout, int rb, int t)
{
    const int b  = rb >> 2;
    const int q  = rb & 3;
    const int t4 = t & 63;
    const int pg = t >> 6;
    const int el = (q << 6) + t4;           // element 0..255 (= k*16+e)
    const float* pp = partial + (size_t)b * (P * 256) + ((pg << 6) * 256) + el;

    float s0 = 0.f, s1 = 0.f, s2 = 0.f, s3 = 0.f;
    #pragma unroll 4
    for (int j = 0; j < 64; j += 4) {
        s0 += pp[(j + 0) * 256];
        s1 += pp[(j + 1) * 256];
        s2 += pp[(j + 2) * 256];
        s3 += pp[(j + 3) * 256];
    }
    red[(pg << 6) + t4] = (s0 + s1) + (s2 + s3);
    __syncthreads();

    if (t < 64) {
        const float val = (red[t4] + red[64 + t4] + red[128 + t4] + red[192 + t4]) * scale;
        float sq = val * val;                // e = el & 15 = t4 & 15
        sq += __shfl_xor(sq, 1);
        sq += __shfl_xor(sq, 2);
        sq += __shfl_xor(sq, 4);
        sq += __shfl_xor(sq, 8);
        const float f = sq / ((1.0f + sq) * sqrtf(sq + EPS));
        float v = val * f;
        if (vprev) v += vprev[(b << 8) + el];
        vout[(b << 8) + el] = v;
    }
    __syncthreads();
}

// XCD-bijective tile mapping (unchanged).
__device__ __forceinline__ void tile_map(int bid, int& p, int& b0, int& i0) {
    const int xcd = bid & 7;
    const int j   = bid >> 3;               // 0..127
    p  = xcd * PPX + (j & (PPX - 1));       // bijective: 8 x 32 x 4 = 1024
    b0 = (j >> 5) * BSET;                   // 0..3 batch groups
    i0 = p * IB;
}

// Stage x tile (unchanged).
__device__ __forceinline__ void stage_x(float* smem, const float* __restrict__ x,
                                        int b0, int i0, int t) {
    const int bl = t >> 4;                  // 0..15
    const int r  = t & 15;                  // float4 within the bl row
    ((float4*)smem)[t] = *(const float4*)(x + ((size_t)(b0 + bl) * In + i0) * Dk + (r << 2));
}

// ---------------- fused cooperative kernel (5 KB LDS) ----------------
// Launched cooperatively (co-residency guarantee) but uses the custom
// two-level barrier instead of cg::grid.sync().
__global__ __launch_bounds__(THREADS)
void caps_fused(const float* __restrict__ x, const float* __restrict__ W,
                int* __restrict__ bar, float* __restrict__ partial,
                float* __restrict__ v0, float* __restrict__ vs,
                float* __restrict__ out)
{
    __shared__ __align__(16) float smem[1280];   // x [0,1024) | red [1024,1280)

    const int t = threadIdx.x, bid = blockIdx.x;
    int p, b0, i0;
    tile_map(bid, p, b0, i0);

    stage_x(smem, x, b0, i0, t);        // once, reused by all 3 iterations
    __syncthreads();

    // r = 0: uniform coupling (1/16 folded into reduce scale)
    iter_body<true>(smem, W, nullptr, partial, p, b0, i0, t);
    grid_bar(bar, 0, bid, t, true, 128);             // full barrier
    if (bid < 256) reduce_phase(smem + 1024, partial, 1.0f / 16.0f, nullptr, v0, bid, t);
    grid_bar(bar, 1, bid, t, bid < 256, 32);         // reduce-arrive barrier

    // r = 1: logits = dot(u_hat, v0);  vs = v0 + v1
    iter_body<false>(smem, W, v0, partial, p, b0, i0, t);
    grid_bar(bar, 2, bid, t, true, 128);
    if (bid < 256) reduce_phase(smem + 1024, partial, 1.0f, v0, vs, bid, t);
    grid_bar(bar, 3, bid, t, bid < 256, 32);

    // r = 2: logits = dot(u_hat, v0 + v1); final squash -> out
    iter_body<false>(smem, W, vs, partial, p, b0, i0, t);
    grid_bar(bar, 4, bid, t, true, 128);
    if (bid < 256) reduce_phase(smem + 1024, partial, 1.0f, nullptr, out, bid, t);
}

// ---------------- fallback: same phases as separate kernels ----------------
template<bool UNIFORM>
__global__ __launch_bounds__(THREADS)
void caps_iter_g(const float* __restrict__ x, const float* __restrict__ W,
                 const float* __restrict__ vsg, float* __restrict__ partial)
{
    __shared__ __align__(16) float smem[1024];
    const int t = threadIdx.x;
    int p, b0, i0;
    tile_map(blockIdx.x, p, b0, i0);
    stage_x(smem, x, b0, i0, t);
    __syncthreads();
    iter_body<UNIFORM>(smem, W, vsg, partial, p, b0, i0, t);
}

__global__ __launch_bounds__(THREADS)
void caps_reduce_g(const float* __restrict__ partial, float scale,
                   const float* __restrict__ vprev, float* __restrict__ vout)
{
    __shared__ __align__(16) float red[256];
    reduce_phase(red, partial, scale, vprev, vout, blockIdx.x, threadIdx.x);
}

extern "C" void kernel_launch(void* const* d_in, const int* in_sizes, int n_in,
                              void* d_out, int out_size, void* d_ws, size_t ws_size,
                              hipStream_t stream) {
    const float* x = (const float*)d_in[0];   // [64, 2048, 8]
    const float* W = (const float*)d_in[1];   // [2048, 16, 8, 16]
    float* out = (float*)d_out;               // [64, 16, 16]
    float* ws  = (float*)d_ws;

    int*   bar     = (int*)ws;                // [2048] ints (5 phases used)
    float* v0      = ws + 2048;               // [64,16,16]
    float* vs      = ws + 2048 + 16384;       // v0 + v1
    float* partial = ws + 2048 + 32768;       // [64][256][256] = 16.8 MB

    // Host-side co-residency gate (capture-safe). Only launch cooperatively
    // if the runtime agrees all 1024 blocks fit.
    int dev = 0;
    hipGetDevice(&dev);
    int numCU = 0;
    hipDeviceGetAttribute(&numCU, hipDeviceAttributeMultiprocessorCount, dev);
    int maxB = 0;
    hipError_t oe = hipOccupancyMaxActiveBlocksPerMultiprocessor(
        &maxB, (const void*)caps_fused, THREADS, 0);
    const bool coop = (oe == hipSuccess) && numCU > 0 &&
                      ((long)maxB * numCU >= BLOCKS);

    if (coop) {
        // Barrier counters MUST be zero at every launch (graph replays do not
        // re-poison ws) -- reset them on-stream before the kernel.
        hipMemsetAsync(bar, 0, 2048 * sizeof(int), stream);
        void* args[] = { (void*)&x, (void*)&W, (void*)&bar, (void*)&partial,
                         (void*)&v0, (void*)&vs, (void*)&out };
        hipLaunchCooperativeKernel((void*)caps_fused, dim3(BLOCKS), dim3(THREADS),
                                   args, 0, stream);
    } else {
        caps_iter_g<true ><<<BLOCKS, THREADS, 0, stream>>>(x, W, nullptr, partial);
        caps_reduce_g<<<256, THREADS, 0, stream>>>(partial, 1.0f / 16.0f, nullptr, v0);
        caps_iter_g<false><<<BLOCKS, THREADS, 0, stream>>>(x, W, v0, partial);
        caps_reduce_g<<<256, THREADS, 0, stream>>>(partial, 1.0f, v0, vs);
        caps_iter_g<false><<<BLOCKS, THREADS, 0, stream>>>(x, W, vs, partial);
        caps_reduce_g<<<256, THREADS, 0, stream>>>(partial, 1.0f, nullptr, out);
    }
}

// Round 16
// 64.314 us; speedup vs baseline: 1.0055x; 1.0055x over previous
//
#include <hip/hip_runtime.h>
#include <hip/hip_cooperative_groups.h>
#include <cstddef>

// Problem constants (from reference)
constexpr int Bn = 64;     // batch
constexpr int In = 2048;   // input capsules
constexpr int Dk = 8;      // input dim
constexpr int Kc = 16;     // output capsules
constexpr int En = 16;     // output dim
constexpr float EPS = 1e-7f;

// Decomposition (R8/R12 measured optimum; R9/R11/R13 sweeps all worse):
// block = (p, g) tile of 8 i's x 16 batches, 4 waves; wave owns 4 batches x
// all 8 i's -> disjoint outputs, barrier-free iter. 1024 blocks co-resident.
constexpr int IB   = 8;            // i's per block
constexpr int P    = In / IB;      // 256 i-chunks
constexpr int BSET = 16;           // batches per block (4 per wave)
constexpr int NBG  = Bn / BSET;    // 4 batch groups
constexpr int BLOCKS = P * NBG;    // 1024
constexpr int THREADS = 256;       // 4 waves
constexpr int PPX  = P / 8;        // 32 p-chunks per XCD (2 MB of W < 4 MB L2)

// Packed fp32 pair -> v_pk_fma_f32. Statically indexed (rule-#20-safe).
typedef float v2f __attribute__((ext_vector_type(2)));
__device__ __forceinline__ v2f fma2(v2f a, v2f b, v2f c) {
    return __builtin_elementwise_fma(a, b, c);
}
__device__ __forceinline__ v2f splat2(float s) { return (v2f){s, s}; }

// DPP cross-lane add on the VALU pipe.
// ctrl: 0xB1 = quad_perm xor1, 0x4E = quad_perm xor2, 0x124/0x128 = row_ror 4/8
template<int CTRL>
__device__ __forceinline__ float dpp_add(float v) {
    int r = __builtin_amdgcn_update_dpp(0, __float_as_int(v), CTRL, 0xF, 0xF, true);
    return v + __int_as_float(r);
}

// ---------------- custom two-level grid barrier (R15, validated) ----------
// 8 per-XCD arrival lines -> master line; lead thread spins with s_sleep.
// Counters zeroed by hipMemsetAsync EVERY launch (replay-safe).
__device__ __forceinline__ void grid_bar(int* __restrict__ bar, int phase,
                                         int bid, int t, bool arrive,
                                         int per_xcd_target)
{
    __syncthreads();                        // all block's stores issued
    if (t == 0) {
        int* slot = bar + phase * 256;
        if (arrive) {
            __threadfence();                // release: device-visible stores
            const int xcd = bid & 7;
            const int prev = __hip_atomic_fetch_add(slot + xcd * 16, 1,
                    __ATOMIC_ACQ_REL, __HIP_MEMORY_SCOPE_AGENT);
            if (prev == per_xcd_target - 1)
                __hip_atomic_fetch_add(slot + 240, 1,
                        __ATOMIC_ACQ_REL, __HIP_MEMORY_SCOPE_AGENT);
        }
        while (__hip_atomic_load(slot + 240, __ATOMIC_ACQUIRE,
                                 __HIP_MEMORY_SCOPE_AGENT) < 8)
            __builtin_amdgcn_s_sleep(2);
        __threadfence();                    // acquire
    }
    __syncthreads();                        // release the block
}

// One routing iteration for a (p, g) tile (R14's pk-math body, unchanged).
template<bool UNIFORM>
__device__ __forceinline__ void iter_body(const float* __restrict__ smemx,
        const float* __restrict__ W, const float* __restrict__ vsg,
        float* __restrict__ partial, int p, int b0, int i0, int t)
{
    const int lane = t & 63;
    const int wvi  = t >> 6;                // 0..3
    const int k    = lane >> 2;             // output capsule
    const int e4   = (lane & 3) << 2;       // first of 4 output dims
    const int bw   = b0 + (wvi << 2);       // this wave's first batch

    v2f vlo[4], vhi[4];
    if (!UNIFORM) {
        #pragma unroll
        for (int b4 = 0; b4 < 4; ++b4) {
            const float4 vv = *(const float4*)(vsg + ((bw + b4) << 8) + k * 16 + e4);
            vlo[b4] = (v2f){vv.x, vv.y};
            vhi[b4] = (v2f){vv.z, vv.w};
        }
    }

    v2f alo[4], ahi[4];
    #pragma unroll
    for (int b4 = 0; b4 < 4; ++b4) { alo[b4] = (v2f){0.f, 0.f}; ahi[b4] = (v2f){0.f, 0.f}; }

    #pragma unroll 2
    for (int ii = 0; ii < IB; ++ii) {
        const int i = i0 + ii;
        const float* wp = W + (size_t)i * (Kc * Dk * En) + k * (Dk * En) + e4;
        v2f wlo[8], whi[8];
        #pragma unroll
        for (int d = 0; d < 8; ++d) {
            const float4 wv = *(const float4*)(wp + d * En);
            wlo[d] = (v2f){wv.x, wv.y};
            whi[d] = (v2f){wv.z, wv.w};
        }

        #pragma unroll
        for (int b4 = 0; b4 < 4; ++b4) {
            const int bl = (wvi << 2) + b4;
            const float* xp = smemx + (((bl << 3) + ii) << 3);  // [bl][ii][*]
            const float4 x0 = *(const float4*)xp;
            const float4 x1 = *(const float4*)(xp + 4);
            const float xs8[8] = {x0.x, x0.y, x0.z, x0.w, x1.x, x1.y, x1.z, x1.w};

            v2f ulo = (v2f){0.f, 0.f}, uhi = (v2f){0.f, 0.f};
            #pragma unroll
            for (int d = 0; d < 8; ++d) {
                const v2f xd = splat2(xs8[d]);
                ulo = fma2(xd, wlo[d], ulo);    // v_pk_fma_f32
                uhi = fma2(xd, whi[d], uhi);
            }

            if (UNIFORM) {
                alo[b4] += ulo;
                ahi[b4] += uhi;
            } else {
                v2f t2 = ulo * vlo[b4];
                t2 = fma2(uhi, vhi[b4], t2);
                float tt = t2.x + t2.y;
                tt = dpp_add<0xB1>(tt);         // e-reduce: quad xor 1
                tt = dpp_add<0x4E>(tt);         // e-reduce: quad xor 2
                const float pe = __expf(tt);    // no max-sub: |tt| small
                float den = dpp_add<0x124>(pe); // k-sum in row: ror 4
                den = dpp_add<0x128>(den);      // k-sum in row: ror 8
                den += __shfl_xor(den, 16);     // cross-row
                den += __shfl_xor(den, 32);
                const float c = pe * __builtin_amdgcn_rcpf(den);
                const v2f cc = splat2(c);
                alo[b4] = fma2(cc, ulo, alo[b4]);
                ahi[b4] = fma2(cc, uhi, ahi[b4]);
            }
        }
    }

    #pragma unroll
    for (int b4 = 0; b4 < 4; ++b4) {
        *(float4*)(partial + ((size_t)(bw + b4) * P + p) * 256 + k * 16 + e4) =
            make_float4(alo[b4].x, alo[b4].y, ahi[b4].x, ahi[b4].y);
    }
}

// ---------------- one-shot v-phase (replaces old strided-scalar reduce) ----
// 256 blocks: rb = (b<<2)|q. Block (b,q) owns els [q*64, q*64+64) of batch b
// = 4 complete capsules (squash normalizes over e only -> block-local).
// Each thread: 16 FULLY-UNROLLED float4 loads (16 outstanding; 1 KB/wave-
// instr) covering (p-range of 16) x (its el-quad); LDS [pg16][el16] combine;
// threads 0..15 finish the p-sum, squash via dpp over e, write vout directly.
// Old reduce: 64 scalar 1KB-stride loads @ 4-ILP = ~16 serial latency rounds;
// this: 1 round of 16 + tiny combine.
__device__ __forceinline__ void v_phase(float4* __restrict__ red4,
        const float* __restrict__ partial, float scale,
        const float* __restrict__ vprev, float* __restrict__ vout, int rb, int t)
{
    const int b    = rb >> 2;
    const int q    = rb & 3;
    const int el16 = t & 15;                // el-quad within the block's 64 els
    const int pg   = t >> 4;                // 0..15 -> p in [pg*16, pg*16+16)
    const float* pp = partial + (size_t)b * (P * 256) + (size_t)(pg * 16) * 256
                    + (q << 6) + (el16 << 2);

    float4 v[16];
    #pragma unroll
    for (int j = 0; j < 16; ++j) v[j] = *(const float4*)(pp + j * 256);
    float4 s = make_float4(0.f, 0.f, 0.f, 0.f);
    #pragma unroll
    for (int j = 0; j < 16; ++j) {
        s.x += v[j].x; s.y += v[j].y; s.z += v[j].z; s.w += v[j].w;
    }
    red4[(pg << 4) + el16] = s;
    __syncthreads();

    if (t < 16) {
        float4 sv = make_float4(0.f, 0.f, 0.f, 0.f);
        #pragma unroll
        for (int g = 0; g < 16; ++g) {
            const float4 a = red4[(g << 4) + t];
            sv.x += a.x; sv.y += a.y; sv.z += a.z; sv.w += a.w;
        }
        sv.x *= scale; sv.y *= scale; sv.z *= scale; sv.w *= scale;
        // squash over e: threads t = k4*4 + e4grp; dpp quad covers the 4 e4's
        float sq = sv.x*sv.x + sv.y*sv.y + sv.z*sv.z + sv.w*sv.w;
        sq = dpp_add<0xB1>(sq);
        sq = dpp_add<0x4E>(sq);
        const float f = sq / ((1.0f + sq) * sqrtf(sq + EPS));
        float4 vv;
        vv.x = sv.x * f; vv.y = sv.y * f; vv.z = sv.z * f; vv.w = sv.w * f;
        const int el4 = (b << 8) + (q << 6) + (t << 2);
        if (vprev) {
            const float4 vp = *(const float4*)(vprev + el4);
            vv.x += vp.x; vv.y += vp.y; vv.z += vp.z; vv.w += vp.w;
        }
        *(float4*)(vout + el4) = vv;
    }
    __syncthreads();
}

// XCD-bijective tile mapping (unchanged).
__device__ __forceinline__ void tile_map(int bid, int& p, int& b0, int& i0) {
    const int xcd = bid & 7;
    const int j   = bid >> 3;               // 0..127
    p  = xcd * PPX + (j & (PPX - 1));       // bijective: 8 x 32 x 4 = 1024
    b0 = (j >> 5) * BSET;                   // 0..3 batch groups
    i0 = p * IB;
}

// Stage x tile (unchanged).
__device__ __forceinline__ void stage_x(float* smem, const float* __restrict__ x,
                                        int b0, int i0, int t) {
    const int bl = t >> 4;                  // 0..15
    const int r  = t & 15;                  // float4 within the bl row
    ((float4*)smem)[t] = *(const float4*)(x + ((size_t)(b0 + bl) * In + i0) * Dk + (r << 2));
}

// ---------------- fused cooperative kernel (8 KB LDS) ----------------
__global__ __launch_bounds__(THREADS)
void caps_fused(const float* __restrict__ x, const float* __restrict__ W,
                int* __restrict__ bar, float* __restrict__ partial,
                float* __restrict__ v0, float* __restrict__ vs,
                float* __restrict__ out)
{
    __shared__ __align__(16) float smem[2048];   // x [0,1024) | red4 [1024,2048)
    float4* red4 = (float4*)(smem + 1024);

    const int t = threadIdx.x, bid = blockIdx.x;
    int p, b0, i0;
    tile_map(bid, p, b0, i0);

    stage_x(smem, x, b0, i0, t);        // once, reused by all 3 iterations
    __syncthreads();

    // r = 0: uniform coupling (1/16 applied in v_phase scale)
    iter_body<true>(smem, W, nullptr, partial, p, b0, i0, t);
    grid_bar(bar, 0, bid, t, true, 128);
    if (bid < 256) v_phase(red4, partial, 1.0f / 16.0f, nullptr, v0, bid, t);
    grid_bar(bar, 1, bid, t, bid < 256, 32);

    // r = 1: logits = dot(u_hat, v0);  vs = v0 + v1
    iter_body<false>(smem, W, v0, partial, p, b0, i0, t);
    grid_bar(bar, 2, bid, t, true, 128);
    if (bid < 256) v_phase(red4, partial, 1.0f, v0, vs, bid, t);
    grid_bar(bar, 3, bid, t, bid < 256, 32);

    // r = 2: logits = dot(u_hat, v0 + v1); final squash -> out
    iter_body<false>(smem, W, vs, partial, p, b0, i0, t);
    grid_bar(bar, 4, bid, t, true, 128);
    if (bid < 256) v_phase(red4, partial, 1.0f, nullptr, out, bid, t);
}

// ---------------- fallback: same phases as separate kernels ----------------
template<bool UNIFORM>
__global__ __launch_bounds__(THREADS)
void caps_iter_g(const float* __restrict__ x, const float* __restrict__ W,
                 const float* __restrict__ vsg, float* __restrict__ partial)
{
    __shared__ __align__(16) float smem[1024];
    const int t = threadIdx.x;
    int p, b0, i0;
    tile_map(blockIdx.x, p, b0, i0);
    stage_x(smem, x, b0, i0, t);
    __syncthreads();
    iter_body<UNIFORM>(smem, W, vsg, partial, p, b0, i0, t);
}

__global__ __launch_bounds__(THREADS)
void caps_reduce_g(const float* __restrict__ partial, float scale,
                   const float* __restrict__ vprev, float* __restrict__ vout)
{
    __shared__ __align__(16) float4 red4[256];
    v_phase(red4, partial, scale, vprev, vout, blockIdx.x, threadIdx.x);
}

extern "C" void kernel_launch(void* const* d_in, const int* in_sizes, int n_in,
                              void* d_out, int out_size, void* d_ws, size_t ws_size,
                              hipStream_t stream) {
    const float* x = (const float*)d_in[0];   // [64, 2048, 8]
    const float* W = (const float*)d_in[1];   // [2048, 16, 8, 16]
    float* out = (float*)d_out;               // [64, 16, 16]
    float* ws  = (float*)d_ws;

    int*   bar     = (int*)ws;                // [2048] ints (5 phases used)
    float* v0      = ws + 2048;               // [64,16,16]
    float* vs      = ws + 2048 + 16384;       // v0 + v1
    float* partial = ws + 2048 + 32768;       // [64][256][256] = 16.8 MB

    // Host-side co-residency gate (capture-safe).
    int dev = 0;
    hipGetDevice(&dev);
    int numCU = 0;
    hipDeviceGetAttribute(&numCU, hipDeviceAttributeMultiprocessorCount, dev);
    int maxB = 0;
    hipError_t oe = hipOccupancyMaxActiveBlocksPerMultiprocessor(
        &maxB, (const void*)caps_fused, THREADS, 0);
    const bool coop = (oe == hipSuccess) && numCU > 0 &&
                      ((long)maxB * numCU >= BLOCKS);

    if (coop) {
        // Barrier counters must be zero at every launch (replay-safe).
        hipMemsetAsync(bar, 0, 2048 * sizeof(int), stream);
        void* args[] = { (void*)&x, (void*)&W, (void*)&bar, (void*)&partial,
                         (void*)&v0, (void*)&vs, (void*)&out };
        hipLaunchCooperativeKernel((void*)caps_fused, dim3(BLOCKS), dim3(THREADS),
                                   args, 0, stream);
    } else {
        caps_iter_g<true ><<<BLOCKS, THREADS, 0, stream>>>(x, W, nullptr, partial);
        caps_reduce_g<<<256, THREADS, 0, stream>>>(partial, 1.0f / 16.0f, nullptr, v0);
        caps_iter_g<false><<<BLOCKS, THREADS, 0, stream>>>(x, W, v0, partial);
        caps_reduce_g<<<256, THREADS, 0, stream>>>(partial, 1.0f, v0, vs);
        caps_iter_g<false><<<BLOCKS, THREADS, 0, stream>>>(x, W, vs, partial);
        caps_reduce_g<<<256, THREADS, 0, stream>>>(partial, 1.0f, nullptr, out);
    }
}